// Round 12
// baseline (129.557 us; speedup 1.0000x reference)
//
#include <hip/hip_runtime.h>

#define CC 8
#define KK 64
#define BB 8192
#define NCHUNK 16
#define NGBLK (NCHUNK * CC)            // 128 gram blocks
#define ROWS_PER_CHUNK (BB / NCHUNK)   // 512

// ---------------- workspace layout (bytes) -----------------------------------------------
// [OFF_G .. OFF_GFST) zeroed by memset 1; gfirst set to 0x7f7f7f7f by memset 2.
#define OFF_G     0                    // f64 G[8][4096]   = 262144 (atomic-accumulated)
#define OFF_GSUM  262144               // f32 gsum[8][64]  =   2048 (atomic-accumulated)
#define OFF_GCNT  264192               // int gcount[8]    =     32
#define OFF_CNTR  264224               // int term counter =      4
#define OFF_FLG   264228               // int invS2 flag   =      4
#define OFF_GFST  264232               // int gfirst[8]    =     32 (0x7f = +inf for atomicMin)
#define OFF_INV   264264               // f64 invS2[4096]  =  32768
#define OFF_LD2   297032               // f64 logdet_total =      8
#define OFF_TERMS 297040               // f64 terms[8]     =     64

// ---------------- k_back LDS layout (double indices) -------------------------------------
#define SM_BUFA  0                     // [64][65] Sigma -> chol ping
#define SM_BUFB  4160                  // [64][65] chol pong
#define SM_PANEL 8320                  // [8][64]  chol panel (also wred[8] post-chol)
#define SM_LB    8832                  // [64][65] class: Sigma_c stash | blk8: normalized L
#define SM_LDI   12992                 // [64]     class: dv            | blk8: 1/L[i][i]
#define SM_MB    13056                 // [64]     mean
#define SM_INTS  13120                 // 16 ints: cnt8s[8], fst8s[8]
#define SMEM_BACK 13128

__device__ __forceinline__ double readlane_f64(double v, int lane) {
  union { double d; int i[2]; } u, r;
  u.d = v;
  r.i[0] = __builtin_amdgcn_readlane(u.i[0], lane);
  r.i[1] = __builtin_amdgcn_readlane(u.i[1], lane);
  return r.d;
}

// ================= D1: gram + stats -> direct device-atomic accumulation ================
__global__ __launch_bounds__(256) void k_front(const float* __restrict__ mu,
                                               const int* __restrict__ labels, char* ws) {
  __shared__ double smem[2176];
  int blk = blockIdx.x;
  int chunk = blk >> 3, c = blk & 7;
  int tid = threadIdx.x;
  int lane = tid & 63, w = tid >> 6;
  int tx = tid & 15, ty = tid >> 4;
  float* rows = (float*)smem;               // [64][64] = 16 KB
  int* labs = (int*)(smem + 2048);
  float* ssum = (float*)(smem + 2080);
  int* scnt = (int*)(smem + 2112);
  int* sfst = (int*)(smem + 2114);
  double* G = (double*)(ws + OFF_G);
  float* gsum = (float*)(ws + OFF_GSUM);
  int* gcount = (int*)(ws + OFF_GCNT);
  int* gfirst = (int*)(ws + OFF_GFST);

  double acc[4][4] = {{0.0}};
  float rsum = 0.f;
  int cnt = 0, first = BB;
  int base = chunk * ROWS_PER_CHUNK;
  const float4* mu4 = (const float4*)mu + (size_t)base * (KK / 4);
  if (tid < KK) ssum[tid] = 0.f;

  float4 pf[4];
  int plab = 0;
#pragma unroll
  for (int i = 0; i < 4; ++i) pf[i] = mu4[tid + i * 256];
  if (tid < 64) plab = labels[base + tid];

#pragma unroll 1
  for (int g = 0; g < ROWS_PER_CHUNK / 64; ++g) {
    __syncthreads();
    float4* rows4 = (float4*)rows;
#pragma unroll
    for (int i = 0; i < 4; ++i) rows4[tid + i * 256] = pf[i];
    if (tid < 64) labs[tid] = plab;
    __syncthreads();
    if (g + 1 < ROWS_PER_CHUNK / 64) {
#pragma unroll
      for (int i = 0; i < 4; ++i) pf[i] = mu4[(g + 1) * 1024 + tid + i * 256];
      if (tid < 64) plab = labels[base + (g + 1) * 64 + tid];
    }
#pragma unroll 4
    for (int r = 0; r < 16; ++r) {
      int rr = w * 16 + r;
      if (labs[rr] == c) rsum += rows[rr * KK + lane];
    }
    if (lane < 16 && labs[w * 16 + lane] == c) {
      cnt++;
      first = min(first, base + g * 64 + w * 16 + lane);
    }
    unsigned long long m = __ballot(labs[lane] == c);
    while (m) {
      int r = __builtin_ctzll(m);
      m &= m - 1;
      const float4* rw4 = (const float4*)(rows + r * KK);
      float4 a4 = rw4[ty], b4 = rw4[tx];
      const float* ai = (const float*)&a4;
      const float* bj = (const float*)&b4;
#pragma unroll
      for (int a = 0; a < 4; ++a)
#pragma unroll
        for (int b = 0; b < 4; ++b) acc[a][b] += (double)ai[a] * (double)bj[b];
    }
  }
  // f64 atomic accumulation into G[c]; distinct addresses within block, 16-way across chunks
  double* Gc = G + (size_t)c * KK * KK;
#pragma unroll
  for (int a = 0; a < 4; ++a)
#pragma unroll
    for (int b = 0; b < 4; ++b)
      atomicAdd(&Gc[(ty * 4 + a) * KK + tx * 4 + b], acc[a][b]);
  atomicAdd(&ssum[lane], rsum);             // LDS-only atomic
#pragma unroll
  for (int off = 32; off; off >>= 1) {
    cnt += __shfl_down(cnt, off);
    first = min(first, __shfl_down(first, off));
  }
  if (lane == 0) { scnt[w] = cnt; sfst[w] = first; }
  __syncthreads();
  if (tid < KK) {
    float v = ssum[tid];
    if (v != 0.f) atomicAdd(&gsum[c * KK + tid], v);
  }
  if (tid == 0) {
    int ct = scnt[0] + scnt[1] + scnt[2] + scnt[3];
    if (ct) {
      atomicAdd(&gcount[c], ct);
      atomicMin(&gfirst[c], min(min(sfst[0], sfst[1]), min(sfst[2], sfst[3])));
    }
  }
}

// ================= 4-wave blocked Cholesky (panel=8, rolled); returns logdet ============
__device__ __noinline__ double chol64(double* smem, bool isS2) {
  int tid = threadIdx.x;
  int t = tid & 63, w = tid >> 6;
  double (*bufA)[KK + 1] = (double (*)[KK + 1])(smem + SM_BUFA);
  double (*bufB)[KK + 1] = (double (*)[KK + 1])(smem + SM_BUFB);
  double (*panelb)[KK] = (double (*)[KK])(smem + SM_PANEL);
  double (*Lb)[KK + 1] = (double (*)[KK + 1])(smem + SM_LB);
  double* Ldi = smem + SM_LDI;
  double (*cur)[KK + 1] = bufA;
  double (*nxt)[KK + 1] = bufB;
  double ldacc = 0.0;
  int bound = t | 7;
#pragma unroll 1
  for (int p = 0; p < 8; ++p) {
    const int P0 = p * 8;
    double cc_[8];
#pragma unroll
    for (int m = 0; m < 8; ++m) cc_[m] = cur[t][P0 + m];
    double uu[8];
    double pd = 1.0;
#pragma unroll
    for (int m = 0; m < 8; ++m) {
      double akk = readlane_f64(cc_[m], P0 + m);   // uniform SGPR lane -> v_readlane
      pd *= akk;
      double inv;
      asm("v_rcp_f64 %0, %1" : "=v"(inv) : "v"(akk));
      inv = inv * fma(-akk, inv, 2.0);             // 1 Newton: rel err ~4e-9
      uu[m] = cc_[m] * inv;
      if (w == 0) {
        panelb[m][t] = cc_[m];
        if (isS2) {
          double rsv = sqrt(akk) * inv;            // 1/sqrt(akk)
          Lb[t][P0 + m] = cc_[m] * rsv;
          if (t == 0) Ldi[P0 + m] = rsv;
        }
      }
#pragma unroll
      for (int mm = m + 1; mm < 8; ++mm)
        cc_[mm] -= uu[m] * readlane_f64(cc_[m], P0 + mm);
    }
    ldacc += log(pd);
    __syncthreads();                    // panelb visible
#pragma unroll 1
    for (int jb = p + 1 + w; jb < 8; jb += 4) {
      int j = jb * 8;
      if (j <= bound) {
        double aj[8];
#pragma unroll
        for (int q = 0; q < 8; ++q) aj[q] = cur[t][j + q];
#pragma unroll
        for (int m = 0; m < 8; ++m)
#pragma unroll
          for (int q = 0; q < 8; ++q) aj[q] -= uu[m] * panelb[m][j + q];
#pragma unroll
        for (int q = 0; q < 8; ++q) nxt[t][j + q] = aj[q];
      }
    }
    __syncthreads();
    { auto tmp = cur; cur = nxt; nxt = tmp; }      // 8 swaps -> cur ends == bufA
  }
  return ldacc;                                    // uniform across threads
}

// ================= D2: 9 blocks; block8 -> flag -> classes (one-directional) =============
__global__ __launch_bounds__(256) void k_back(const float* __restrict__ cov,
                                              float* out, char* ws) {
  __shared__ double smem[SMEM_BACK];
  int blk = blockIdx.x;
  int tid = threadIdx.x;
  int t = tid & 63, w = tid >> 6;
  double* G = (double*)(ws + OFF_G);
  float* gsum = (float*)(ws + OFF_GSUM);
  int* gcount = (int*)(ws + OFF_GCNT);
  int* gfirst = (int*)(ws + OFF_GFST);
  double* invS2 = (double*)(ws + OFF_INV);
  double* ld2g = (double*)(ws + OFF_LD2);
  double* terms = (double*)(ws + OFF_TERMS);
  int* cntr = (int*)(ws + OFF_CNTR);
  int* flg = (int*)(ws + OFF_FLG);
  double* mb = smem + SM_MB;
  int* cnt8s = (int*)(smem + SM_INTS);
  int* fst8s = cnt8s + 8;

  if (blk < CC) {
    int c = blk;
    // ---- A: tiny stats (gsum rows + counts/firsts) ----
    if (tid < 64) {
      double st = 0.0;
#pragma unroll
      for (int cc2 = 0; cc2 < CC; ++cc2) st += (double)gsum[cc2 * KK + t];
      smem[SM_LDI + t] = st * (1.0 / (double)BB);     // mtot (temp)
      smem[SM_MB + t] = (double)gsum[c * KK + t];     // raw own sum
    } else if (tid < 80) {
      int j = tid - 64;
      if (j < 8) cnt8s[j] = gcount[j];
      else fst8s[j - 8] = gfirst[j - 8];
    }
    __syncthreads();
    int nc = cnt8s[c];
    double ncd = (double)nc;
    double safe = nc > 0 ? ncd : 1.0;
    double inv_safe = 1.0 / safe;
    if (tid < 64) {
      double m = smem[SM_MB + t] * inv_safe;
      smem[SM_MB + t] = m;
      smem[SM_LDI + t] -= m;                          // dv = mtot - mean
    }
    __syncthreads();

    // ---- B: read G_c (32 KB, coalesced) -> build Sigma_c into bufA + stash ----
    double* stash = smem + SM_LB;                     // untouched by chol(!isS2)
    const double* Gc = G + (size_t)c * KK * KK;
#pragma unroll
    for (int q = 0; q < 16; ++q) {
      int e = tid + q * 256;
      int r = e >> 6, c0 = e & 63;
      double v = (double)cov[e] + (Gc[e] - ncd * mb[r] * mb[c0]) * inv_safe;
      smem[SM_BUFA + r * (KK + 1) + c0] = v;
      stash[r * (KK + 1) + c0] = v;
    }
    __syncthreads();

    // ---- C: own Cholesky (overlaps block 8's chol/solve) ----
    double ld1 = chol64(smem, false);

    // ---- D: wait for invS2, then combine ----
    if (tid == 0) {
      int it = 0;
      while (__hip_atomic_load(flg, __ATOMIC_ACQUIRE, __HIP_MEMORY_SCOPE_AGENT) == 0 &&
             ++it < (1 << 20))
        __builtin_amdgcn_s_sleep(8);
    }
    __syncthreads();
    double ld2 = __hip_atomic_load(ld2g, __ATOMIC_RELAXED, __HIP_MEMORY_SCOPE_AGENT);
    double* dvv = smem + SM_LDI;
    double trp = 0.0, qp = 0.0;
#pragma unroll 4
    for (int rr = 0; rr < 16; ++rr) {
      int r = w * 16 + rr;
      double iv = __hip_atomic_load(&invS2[r * KK + t], __ATOMIC_RELAXED,
                                    __HIP_MEMORY_SCOPE_AGENT);
      trp += iv * stash[r * (KK + 1) + t];
      qp += iv * dvv[r];
    }
    qp *= dvv[t];
#pragma unroll
    for (int m = 32; m; m >>= 1) {
      trp += __shfl_down(trp, m);
      qp += __shfl_down(qp, m);
    }
    double* wred = smem + SM_PANEL;                   // dead post-chol
    if (t == 0) { wred[w * 2] = trp; wred[w * 2 + 1] = qp; }
    __syncthreads();
    if (tid == 0) {
      double tr = wred[0] + wred[2] + wred[4] + wred[6];
      double quad = wred[1] + wred[3] + wred[5] + wred[7];
      int best = 0;
      long long bv = -2;
      for (int j = 0; j < CC; ++j) {
        long long v = cnt8s[j] > 0 ? (long long)fst8s[j] : -1;
        if (v > bv) { bv = v; best = j; }             // strict > == argmax tie-break
      }
      double kl = 0.5 * (tr + quad - (double)KK + ld2 - ld1);
      double wgt = (nc > 0 && c != best) ? ncd : 0.0;
      double term = kl * wgt / (double)BB;
      atomicExch((unsigned long long*)&terms[c],
                 (unsigned long long)__double_as_longlong(term));
      __threadfence();
      int old = atomicAdd(cntr, 1);
      if (old == CC - 1) {                            // last arriver gathers + writes
        double s = 0.0;
        for (int j = 0; j < CC; ++j) s += atomicAdd(&terms[j], 0.0);
        out[0] = (float)s;
      }
    }
  } else {
    // ---- block 8: no waiting. mtot ----
    if (tid < 64) {
      double st = 0.0;
#pragma unroll
      for (int cc2 = 0; cc2 < CC; ++cc2) st += (double)gsum[cc2 * KK + t];
      mb[t] = st * (1.0 / (double)BB);
    }
    __syncthreads();
    // ---- build Sigma_total = cov + (sum_c G_c)/B - m m^T ----
    const double invB = 1.0 / (double)BB;
#pragma unroll 1
    for (int q = 0; q < 16; ++q) {
      int e = tid + q * 256;
      double g = 0.0;
#pragma unroll
      for (int c2 = 0; c2 < CC; ++c2) g += G[(size_t)c2 * KK * KK + e];  // 8 pipelined loads
      int r = e >> 6, c0 = e & 63;
      smem[SM_BUFA + r * (KK + 1) + c0] = (double)cov[e] + g * invB - mb[r] * mb[c0];
    }
    __syncthreads();
    double ld2 = chol64(smem, true);
    // ---- X = L^{-1} (wave 0; Xs stride-64 overlays dead bufA) ----
    double (*Xs)[KK] = (double (*)[KK])(smem + SM_BUFA);
    if (w == 0) {
      double (*Lb)[KK + 1] = (double (*)[KK + 1])(smem + SM_LB);
      double* Ldi = smem + SM_LDI;
#pragma unroll 1
      for (int g = 0; g < 8; ++g) {
        int I0 = g * 8;
        double sv[8];
#pragma unroll
        for (int m = 0; m < 8; ++m) sv[m] = 0.0;
#pragma unroll 2
        for (int j = 0; j < I0; ++j) {
          double xj = Xs[j][t];                       // lane-consecutive
#pragma unroll
          for (int m = 0; m < 8; ++m) sv[m] += Lb[I0 + m][j] * xj;  // broadcast
        }
#pragma unroll
        for (int m = 0; m < 8; ++m) {
          int i = I0 + m;
          double x = (((i == t) ? 1.0 : 0.0) - sv[m]) * Ldi[i];
#pragma unroll
          for (int mm = m + 1; mm < 8; ++mm) sv[mm] += Lb[I0 + mm][i] * x;
          Xs[i][t] = x;                               // zeros for i<t fall out naturally
        }
      }
    }
    __syncthreads();
    // ---- invS2 = X^T X (agent-scope stores) ----
#pragma unroll 1
    for (int rr = 0; rr < 16; ++rr) {
      int r = w + rr * 4;
      int k0 = r > t ? r : t;
      double s = 0.0;
#pragma unroll 2
      for (int k = k0; k < KK; ++k) s += Xs[k][r] * Xs[k][t];
      __hip_atomic_store(&invS2[r * KK + t], s, __ATOMIC_RELAXED, __HIP_MEMORY_SCOPE_AGENT);
    }
    __syncthreads();                                  // drains stores (vmcnt)
    if (tid == 0) {
      __hip_atomic_store(ld2g, ld2, __ATOMIC_RELAXED, __HIP_MEMORY_SCOPE_AGENT);
      __threadfence();
      __hip_atomic_store(flg, 1, __ATOMIC_RELEASE, __HIP_MEMORY_SCOPE_AGENT);
    }
  }
}

extern "C" void kernel_launch(void* const* d_in, const int* in_sizes, int n_in,
                              void* d_out, int out_size, void* d_ws, size_t ws_size,
                              hipStream_t stream) {
  (void)in_sizes; (void)n_in; (void)out_size; (void)ws_size;
  const float* mu = (const float*)d_in[0];
  const int* labels = (const int*)d_in[1];
  const float* cov = (const float*)d_in[2];
  float* out = (float*)d_out;
  char* ws = (char*)d_ws;

  // zero G+gsum+gcount+cntr+flg; gfirst -> 0x7f7f7f7f (acts as +inf for atomicMin)
  hipMemsetAsync(ws, 0, OFF_GFST, stream);
  hipMemsetAsync(ws + OFF_GFST, 0x7f, CC * sizeof(int), stream);

  k_front<<<NGBLK, 256, 0, stream>>>(mu, labels, ws);
  k_back<<<CC + 1, 256, 0, stream>>>(cov, out, ws);
}

// Round 13
// 111.081 us; speedup vs baseline: 1.1663x; 1.1663x over previous
//
#include <hip/hip_runtime.h>

#define CC 8
#define KK 64
#define BB 8192
#define NCHUNK 16
#define NGBLK (NCHUNK * CC)            // 128 gram blocks
#define ROWS_PER_CHUNK (BB / NCHUNK)   // 512

// ---------------- workspace layout (bytes) -----------------------------------------------
// [OFF_G .. OFF_GFST) zeroed by memset 1; gfirst set to 0x7f7f7f7f by memset 2.
#define OFF_G     0                    // f64 G[8][4096]   = 262144 (atomic-accumulated)
#define OFF_GSUM  262144               // f32 gsum[8][64]  =   2048 (atomic-accumulated)
#define OFF_GCNT  264192               // int gcount[8]    =     32
#define OFF_CNTR  264224               // int term counter =      4
#define OFF_FLG   264228               // int invS2 flag   =      4
#define OFF_GFST  264232               // int gfirst[8]    =     32 (0x7f = +inf for atomicMin)
#define OFF_INV   264264               // f64 invS2[4096]  =  32768
#define OFF_LD2   297032               // f64 logdet_total =      8
#define OFF_TERMS 297040               // f64 terms[8]     =     64

// ---------------- k_back LDS layout (double indices) -------------------------------------
#define SM_BUFA  0                     // [64][65] Sigma -> in-place chol; Xs overlays after
#define SM_SPART 4160                  // solve partials [4][8][64] = 2048
#define SM_PANEL 8320                  // wred[8] (combine scratch)
#define SM_LB    8832                  // [64][65] class: Sigma_c stash | blk8: normalized L
#define SM_LDI   12992                 // [64]     class: dv            | blk8: 1/L[i][i]
#define SM_MB    13056                 // [64]     mean
#define SM_INTS  13120                 // 16 ints: cnt8s[8], fst8s[8]
#define SMEM_BACK 13128

__device__ __forceinline__ double readlane_f64(double v, int lane) {
  union { double d; int i[2]; } u, r;
  u.d = v;
  r.i[0] = __builtin_amdgcn_readlane(u.i[0], lane);
  r.i[1] = __builtin_amdgcn_readlane(u.i[1], lane);
  return r.d;
}

// ================= D1: gram + stats -> direct device-atomic accumulation ================
__global__ __launch_bounds__(256) void k_front(const float* __restrict__ mu,
                                               const int* __restrict__ labels, char* ws) {
  __shared__ double smem[2176];
  int blk = blockIdx.x;
  int chunk = blk >> 3, c = blk & 7;
  int tid = threadIdx.x;
  int lane = tid & 63, w = tid >> 6;
  int tx = tid & 15, ty = tid >> 4;
  float* rows = (float*)smem;               // [64][64] = 16 KB
  int* labs = (int*)(smem + 2048);
  float* ssum = (float*)(smem + 2080);
  int* scnt = (int*)(smem + 2112);
  int* sfst = (int*)(smem + 2114);
  double* G = (double*)(ws + OFF_G);
  float* gsum = (float*)(ws + OFF_GSUM);
  int* gcount = (int*)(ws + OFF_GCNT);
  int* gfirst = (int*)(ws + OFF_GFST);

  double acc[4][4] = {{0.0}};
  float rsum = 0.f;
  int cnt = 0, first = BB;
  int base = chunk * ROWS_PER_CHUNK;
  const float4* mu4 = (const float4*)mu + (size_t)base * (KK / 4);
  if (tid < KK) ssum[tid] = 0.f;

  float4 pf[4];
  int plab = 0;
#pragma unroll
  for (int i = 0; i < 4; ++i) pf[i] = mu4[tid + i * 256];
  if (tid < 64) plab = labels[base + tid];

#pragma unroll 1
  for (int g = 0; g < ROWS_PER_CHUNK / 64; ++g) {
    __syncthreads();
    float4* rows4 = (float4*)rows;
#pragma unroll
    for (int i = 0; i < 4; ++i) rows4[tid + i * 256] = pf[i];
    if (tid < 64) labs[tid] = plab;
    __syncthreads();
    if (g + 1 < ROWS_PER_CHUNK / 64) {
#pragma unroll
      for (int i = 0; i < 4; ++i) pf[i] = mu4[(g + 1) * 1024 + tid + i * 256];
      if (tid < 64) plab = labels[base + (g + 1) * 64 + tid];
    }
#pragma unroll 4
    for (int r = 0; r < 16; ++r) {
      int rr = w * 16 + r;
      if (labs[rr] == c) rsum += rows[rr * KK + lane];
    }
    if (lane < 16 && labs[w * 16 + lane] == c) {
      cnt++;
      first = min(first, base + g * 64 + w * 16 + lane);
    }
    unsigned long long m = __ballot(labs[lane] == c);
    while (m) {
      int r = __builtin_ctzll(m);
      m &= m - 1;
      const float4* rw4 = (const float4*)(rows + r * KK);
      float4 a4 = rw4[ty], b4 = rw4[tx];
      const float* ai = (const float*)&a4;
      const float* bj = (const float*)&b4;
#pragma unroll
      for (int a = 0; a < 4; ++a)
#pragma unroll
        for (int b = 0; b < 4; ++b) acc[a][b] += (double)ai[a] * (double)bj[b];
    }
  }
  double* Gc = G + (size_t)c * KK * KK;
#pragma unroll
  for (int a = 0; a < 4; ++a)
#pragma unroll
    for (int b = 0; b < 4; ++b)
      atomicAdd(&Gc[(ty * 4 + a) * KK + tx * 4 + b], acc[a][b]);
  atomicAdd(&ssum[lane], rsum);             // LDS-only atomic
#pragma unroll
  for (int off = 32; off; off >>= 1) {
    cnt += __shfl_down(cnt, off);
    first = min(first, __shfl_down(first, off));
  }
  if (lane == 0) { scnt[w] = cnt; sfst[w] = first; }
  __syncthreads();
  if (tid < KK) {
    float v = ssum[tid];
    if (v != 0.f) atomicAdd(&gsum[c * KK + tid], v);
  }
  if (tid == 0) {
    int ct = scnt[0] + scnt[1] + scnt[2] + scnt[3];
    if (ct) {
      atomicAdd(&gcount[c], ct);
      atomicMin(&gfirst[c], min(min(sfst[0], sfst[1]), min(sfst[2], sfst[3])));
    }
  }
}

// ========== 4-wave blocked Cholesky v2: IN-PLACE, readlane trailing, 8 barriers ==========
// Panel columns live in every wave's registers (redundant factor); trailing updates pull
// them via v_readlane (SALU) instead of LDS broadcasts. Each lane RMWs only its own row.
__device__ __noinline__ double chol64(double* smem, bool isS2) {
  int tid = threadIdx.x;
  int t = tid & 63, w = tid >> 6;
  double (*A)[KK + 1] = (double (*)[KK + 1])(smem + SM_BUFA);
  double (*Lb)[KK + 1] = (double (*)[KK + 1])(smem + SM_LB);
  double* Ldi = smem + SM_LDI;
  double ldacc = 0.0;
  int bound = t | 7;
#pragma unroll 1
  for (int p = 0; p < 8; ++p) {
    const int P0 = p * 8;
    double cc_[8];
#pragma unroll
    for (int m = 0; m < 8; ++m) cc_[m] = A[t][P0 + m];
    double uu[8];
    double pd = 1.0;
#pragma unroll
    for (int m = 0; m < 8; ++m) {
      double akk = readlane_f64(cc_[m], P0 + m);   // uniform SGPR lane -> v_readlane
      pd *= akk;
      double inv;
      asm("v_rcp_f64 %0, %1" : "=v"(inv) : "v"(akk));
      inv = inv * fma(-akk, inv, 2.0);             // 1 Newton: rel err ~4e-9
      uu[m] = cc_[m] * inv;
      if (isS2 && w == 0) {
        double rsv = sqrt(akk) * inv;              // 1/sqrt(akk)
        Lb[t][P0 + m] = cc_[m] * rsv;
        if (t == 0) Ldi[P0 + m] = rsv;
      }
#pragma unroll
      for (int mm = m + 1; mm < 8; ++mm)
        cc_[mm] -= uu[m] * readlane_f64(cc_[m], P0 + mm);
    }
    ldacc += log(pd);
    // trailing update: in place, wave-split by j-block, panel via readlane (no LDS)
#pragma unroll 1
    for (int jb = p + 1 + w; jb < 8; jb += 4) {
      int j = jb * 8;
      if (j <= bound) {
        double aj[8];
#pragma unroll
        for (int q = 0; q < 8; ++q) aj[q] = A[t][j + q];
#pragma unroll
        for (int m = 0; m < 8; ++m) {
          double u = uu[m];
#pragma unroll
          for (int q = 0; q < 8; ++q)
            aj[q] -= u * readlane_f64(cc_[m], j + q);   // panelb[m][j+q] from lane regs
        }
#pragma unroll
        for (int q = 0; q < 8; ++q) A[t][j + q] = aj[q];
      }
    }
    __syncthreads();                    // next panel's columns (written by one wave) visible
  }
  return ldacc;                          // uniform across threads
}

// ================= D2: 9 blocks; block8 -> flag -> classes (one-directional) =============
__global__ __launch_bounds__(256) void k_back(const float* __restrict__ cov,
                                              float* out, char* ws) {
  __shared__ double smem[SMEM_BACK];
  int blk = blockIdx.x;
  int tid = threadIdx.x;
  int t = tid & 63, w = tid >> 6;
  double* G = (double*)(ws + OFF_G);
  float* gsum = (float*)(ws + OFF_GSUM);
  int* gcount = (int*)(ws + OFF_GCNT);
  int* gfirst = (int*)(ws + OFF_GFST);
  double* invS2 = (double*)(ws + OFF_INV);
  double* ld2g = (double*)(ws + OFF_LD2);
  double* terms = (double*)(ws + OFF_TERMS);
  int* cntr = (int*)(ws + OFF_CNTR);
  int* flg = (int*)(ws + OFF_FLG);
  double* mb = smem + SM_MB;
  int* cnt8s = (int*)(smem + SM_INTS);
  int* fst8s = cnt8s + 8;

  if (blk < CC) {
    int c = blk;
    // ---- A: tiny stats ----
    if (tid < 64) {
      double st = 0.0;
#pragma unroll
      for (int cc2 = 0; cc2 < CC; ++cc2) st += (double)gsum[cc2 * KK + t];
      smem[SM_LDI + t] = st * (1.0 / (double)BB);     // mtot (temp)
      smem[SM_MB + t] = (double)gsum[c * KK + t];     // raw own sum
    } else if (tid < 80) {
      int j = tid - 64;
      if (j < 8) cnt8s[j] = gcount[j];
      else fst8s[j - 8] = gfirst[j - 8];
    }
    __syncthreads();
    int nc = cnt8s[c];
    double ncd = (double)nc;
    double safe = nc > 0 ? ncd : 1.0;
    double inv_safe = 1.0 / safe;
    if (tid < 64) {
      double m = smem[SM_MB + t] * inv_safe;
      smem[SM_MB + t] = m;
      smem[SM_LDI + t] -= m;                          // dv = mtot - mean
    }
    __syncthreads();

    // ---- B: read G_c (32 KB, coalesced) -> build Sigma_c into bufA + stash ----
    double* stash = smem + SM_LB;                     // untouched by chol(!isS2)
    const double* Gc = G + (size_t)c * KK * KK;
#pragma unroll
    for (int q = 0; q < 16; ++q) {
      int e = tid + q * 256;
      int r = e >> 6, c0 = e & 63;
      double v = (double)cov[e] + (Gc[e] - ncd * mb[r] * mb[c0]) * inv_safe;
      smem[SM_BUFA + r * (KK + 1) + c0] = v;
      stash[r * (KK + 1) + c0] = v;
    }
    __syncthreads();

    // ---- C: own Cholesky (overlaps block 8's chol/solve) ----
    double ld1 = chol64(smem, false);

    // ---- D: wait for invS2, then combine ----
    if (tid == 0) {
      int it = 0;
      while (__hip_atomic_load(flg, __ATOMIC_ACQUIRE, __HIP_MEMORY_SCOPE_AGENT) == 0 &&
             ++it < (1 << 20))
        __builtin_amdgcn_s_sleep(8);
    }
    __syncthreads();
    double ld2 = __hip_atomic_load(ld2g, __ATOMIC_RELAXED, __HIP_MEMORY_SCOPE_AGENT);
    double* dvv = smem + SM_LDI;
    double trp = 0.0, qp = 0.0;
#pragma unroll 4
    for (int rr = 0; rr < 16; ++rr) {
      int r = w * 16 + rr;
      double iv = __hip_atomic_load(&invS2[r * KK + t], __ATOMIC_RELAXED,
                                    __HIP_MEMORY_SCOPE_AGENT);
      trp += iv * stash[r * (KK + 1) + t];
      qp += iv * dvv[r];
    }
    qp *= dvv[t];
#pragma unroll
    for (int m = 32; m; m >>= 1) {
      trp += __shfl_down(trp, m);
      qp += __shfl_down(qp, m);
    }
    double* wred = smem + SM_PANEL;
    if (t == 0) { wred[w * 2] = trp; wred[w * 2 + 1] = qp; }
    __syncthreads();
    if (tid == 0) {
      double tr = wred[0] + wred[2] + wred[4] + wred[6];
      double quad = wred[1] + wred[3] + wred[5] + wred[7];
      int best = 0;
      long long bv = -2;
      for (int j = 0; j < CC; ++j) {
        long long v = cnt8s[j] > 0 ? (long long)fst8s[j] : -1;
        if (v > bv) { bv = v; best = j; }             // strict > == argmax tie-break
      }
      double kl = 0.5 * (tr + quad - (double)KK + ld2 - ld1);
      double wgt = (nc > 0 && c != best) ? ncd : 0.0;
      double term = kl * wgt / (double)BB;
      atomicExch((unsigned long long*)&terms[c],
                 (unsigned long long)__double_as_longlong(term));
      __threadfence();
      int old = atomicAdd(cntr, 1);
      if (old == CC - 1) {                            // last arriver gathers + writes
        double s = 0.0;
        for (int j = 0; j < CC; ++j) s += atomicAdd(&terms[j], 0.0);
        out[0] = (float)s;
      }
    }
  } else {
    // ---- block 8: mtot ----
    if (tid < 64) {
      double st = 0.0;
#pragma unroll
      for (int cc2 = 0; cc2 < CC; ++cc2) st += (double)gsum[cc2 * KK + t];
      mb[t] = st * (1.0 / (double)BB);
    }
    __syncthreads();
    // ---- build Sigma_total = cov + (sum_c G_c)/B - m m^T ----
    const double invB = 1.0 / (double)BB;
#pragma unroll 1
    for (int q = 0; q < 16; ++q) {
      int e = tid + q * 256;
      double g = 0.0;
#pragma unroll
      for (int c2 = 0; c2 < CC; ++c2) g += G[(size_t)c2 * KK * KK + e];  // 8 pipelined loads
      int r = e >> 6, c0 = e & 63;
      smem[SM_BUFA + r * (KK + 1) + c0] = (double)cov[e] + g * invB - mb[r] * mb[c0];
    }
    __syncthreads();
    double ld2 = chol64(smem, true);
    // ---- X = L^{-1}: 4-wave striped partial sums, wave-0 serial finish per group ----
    double (*Xs)[KK] = (double (*)[KK])(smem + SM_BUFA);   // stride-64 overlay of dead bufA
    double (*Lb)[KK + 1] = (double (*)[KK + 1])(smem + SM_LB);
    double* Ldi = smem + SM_LDI;
    double* spart = smem + SM_SPART;                       // [4][8][64]
#pragma unroll 1
    for (int g = 0; g < 8; ++g) {
      int I0 = g * 8;
      double sv[8];
#pragma unroll
      for (int m = 0; m < 8; ++m) sv[m] = 0.0;
#pragma unroll 1
      for (int j = w; j < I0; j += 4) {                    // wave-strided partials
        double xj = Xs[j][t];                              // lane-consecutive
#pragma unroll
        for (int m = 0; m < 8; ++m) sv[m] += Lb[I0 + m][j] * xj;  // broadcast
      }
#pragma unroll
      for (int m = 0; m < 8; ++m) spart[(w * 8 + m) * 64 + t] = sv[m];
      __syncthreads();
      if (w == 0) {
        double sv2[8];
#pragma unroll
        for (int m = 0; m < 8; ++m)
          sv2[m] = spart[m * 64 + t] + spart[(8 + m) * 64 + t] +
                   spart[(16 + m) * 64 + t] + spart[(24 + m) * 64 + t];
#pragma unroll
        for (int m = 0; m < 8; ++m) {
          int i = I0 + m;
          double x = (((i == t) ? 1.0 : 0.0) - sv2[m]) * Ldi[i];
#pragma unroll
          for (int mm = m + 1; mm < 8; ++mm) sv2[mm] += Lb[I0 + mm][i] * x;
          Xs[i][t] = x;                                    // zeros for i<t fall out naturally
        }
      }
      __syncthreads();
    }
    // ---- invS2 = X^T X via register-cached own column + readlane (no LDS broadcasts) ----
    {
      double s[16];
#pragma unroll
      for (int rr = 0; rr < 16; ++rr) s[rr] = 0.0;
#pragma unroll 1
      for (int half = 0; half < 2; ++half) {
        double xt[32];
        int kb = half * 32;
#pragma unroll
        for (int kk = 0; kk < 32; ++kk) xt[kk] = Xs[kb + kk][t];  // lane-consecutive
#pragma unroll 1
        for (int rr = 0; rr < 16; ++rr) {
          int r = w + rr * 4;                              // uniform per wave
          double acc2 = 0.0;
#pragma unroll
          for (int kk = 0; kk < 32; ++kk)
            acc2 += readlane_f64(xt[kk], r) * xt[kk];      // X[k][r]*X[k][t]; zeros handle k0
          s[rr] += acc2;
        }
      }
#pragma unroll 1
      for (int rr = 0; rr < 16; ++rr) {
        int r = w + rr * 4;
        __hip_atomic_store(&invS2[r * KK + t], s[rr], __ATOMIC_RELAXED,
                           __HIP_MEMORY_SCOPE_AGENT);
      }
    }
    __syncthreads();                                      // drains stores (vmcnt)
    if (tid == 0) {
      __hip_atomic_store(ld2g, ld2, __ATOMIC_RELAXED, __HIP_MEMORY_SCOPE_AGENT);
      __threadfence();
      __hip_atomic_store(flg, 1, __ATOMIC_RELEASE, __HIP_MEMORY_SCOPE_AGENT);
    }
  }
}

extern "C" void kernel_launch(void* const* d_in, const int* in_sizes, int n_in,
                              void* d_out, int out_size, void* d_ws, size_t ws_size,
                              hipStream_t stream) {
  (void)in_sizes; (void)n_in; (void)out_size; (void)ws_size;
  const float* mu = (const float*)d_in[0];
  const int* labels = (const int*)d_in[1];
  const float* cov = (const float*)d_in[2];
  float* out = (float*)d_out;
  char* ws = (char*)d_ws;

  // zero G+gsum+gcount+cntr+flg; gfirst -> 0x7f7f7f7f (acts as +inf for atomicMin)
  hipMemsetAsync(ws, 0, OFF_GFST, stream);
  hipMemsetAsync(ws + OFF_GFST, 0x7f, CC * sizeof(int), stream);

  k_front<<<NGBLK, 256, 0, stream>>>(mu, labels, ws);
  k_back<<<CC + 1, 256, 0, stream>>>(cov, out, ws);
}